// Round 21
// baseline (200.177 us; speedup 1.0000x reference)
//
#include <hip/hip_runtime.h>
#include <hip/hip_bf16.h>

#define S_LEN 2048
#define DMODEL 2048
#define NHEAD 16
#define NKVH 2
#define HDIM 128
#define NROW 4096   // B*S
#define NQKV 2560   // 2048 + 256 + 256
#define SCALE 0.08838834764831845f
#define LOG2E 1.4426950408889634f

using short8 = __attribute__((ext_vector_type(8))) short;
using bf16x8 = __attribute__((ext_vector_type(8))) __bf16;
using f32x4  = __attribute__((ext_vector_type(4))) float;

__device__ __forceinline__ f32x4 mfma16(short8 a, short8 b, f32x4 c) {
  return __builtin_amdgcn_mfma_f32_16x16x32_bf16(
      __builtin_bit_cast(bf16x8, a), __builtin_bit_cast(bf16x8, b), c, 0, 0, 0);
}

__device__ __forceinline__ void gload_lds16(const void* g, void* l) {
  __builtin_amdgcn_global_load_lds(
      (const __attribute__((address_space(1))) unsigned int*)g,
      (__attribute__((address_space(3))) unsigned int*)l, 16, 0, 0);
}

__device__ __forceinline__ float fast_exp2(float x) {
  return __builtin_amdgcn_exp2f(x);   // raw v_exp_f32 (2^x), no libm wrapper
}

__device__ __forceinline__ void storeC(float* C, long idx, float v) { C[idx] = v; }
__device__ __forceinline__ void storeC(__hip_bfloat16* C, long idx, float v) {
  C[idx] = __float2bfloat16(v);
}

__device__ __forceinline__ unsigned short bf16bits(float f) {
  __hip_bfloat16 h = __float2bfloat16(f);
  return *(unsigned short*)&h;
}

// ---------------- fused prep: conv_x | convT3(Wq,Wk,Wv) | convT(Wo) | mk_table ----------------
__global__ void prep_kernel(const float* __restrict__ x, __hip_bfloat16* __restrict__ xb,
                            const float* __restrict__ Wq, const float* __restrict__ Wk,
                            const float* __restrict__ Wv, __hip_bfloat16* __restrict__ wt1,
                            const float* __restrict__ Wo, __hip_bfloat16* __restrict__ wto,
                            float* __restrict__ cost, float* __restrict__ sint) {
  __shared__ float t[32][33];
  const int bid = blockIdx.x;
  const int tid = threadIdx.x;
  if (bid < 8192) {
    long i = ((long)bid * 256 + tid) * 4;
    float4 v = *(const float4*)(x + i);
    __hip_bfloat16 o[4];
    o[0] = __float2bfloat16(v.x); o[1] = __float2bfloat16(v.y);
    o[2] = __float2bfloat16(v.z); o[3] = __float2bfloat16(v.w);
    *(ushort4*)(xb + i) = *(const ushort4*)o;
  } else if (bid < 17408) {
    int tx = tid & 31, ty = tid >> 5;
    const float* src; int Ns, n0, row_off, kt;
    __hip_bfloat16* dst;
    if (bid < 13312) {
      int r = bid - 8192;            // 5120 blocks: nt 0..79, kt 0..63
      int nt = r % 80; kt = r / 80;
      dst = wt1;
      if (nt < 64)      { src = Wq; Ns = 2048; n0 = nt * 32;        row_off = n0; }
      else if (nt < 72) { src = Wk; Ns = 256;  n0 = (nt - 64) * 32; row_off = 2048 + n0; }
      else              { src = Wv; Ns = 256;  n0 = (nt - 72) * 32; row_off = 2304 + n0; }
    } else {
      int r = bid - 13312;           // 4096 blocks
      int nt = r % 64; kt = r / 64;
      src = Wo; Ns = 2048; n0 = nt * 32; row_off = n0;
      dst = wto;
    }
#pragma unroll
    for (int i = 0; i < 4; i++)
      t[ty + i * 8][tx] = src[(long)(kt * 32 + ty + i * 8) * Ns + n0 + tx];
    __syncthreads();
#pragma unroll
    for (int i = 0; i < 4; i++)
      dst[(long)(row_off + ty + i * 8) * 2048 + kt * 32 + tx] =
          __float2bfloat16(t[tx][ty + i * 8]);
  } else {
    int i = (bid - 17408) * 256 + tid;  // < 131072
    int s = i >> 6, j = i & 63;
    float f = powf(10000.0f, -(float)j / 64.0f);
    float a = (float)s * f;
    cost[i] = cosf(a);
    sint[i] = sinf(a);
  }
}

// ---------------- m97-style GEMM, BK=64, double-buffered LDS ----------------
// Prefetch next 64-K tile into the other buffer at the top of the iteration,
// compute current buffer, ONE __syncthreads per iteration (drain finds the
// prefetch already landed -> overlap; R5-attn-proven pattern). LDS 64 KB.
template <typename OutT>
__global__ void gemm_bt(const __hip_bfloat16* __restrict__ A,
                        const __hip_bfloat16* __restrict__ Bt,
                        OutT* __restrict__ C, int M, int N, int K) {
  __shared__ __align__(16) __hip_bfloat16 a_lds[2][2][128 * 32];
  __shared__ __align__(16) __hip_bfloat16 b_lds[2][2][128 * 32];
  const int tid = threadIdx.x;
  const int wid = tid >> 6, lane = tid & 63;
  const int nbx = gridDim.x;
  int bid = blockIdx.y * nbx + blockIdx.x;
  const int nwg = nbx * gridDim.y;
  bid = (bid & 7) * (nwg >> 3) + (bid >> 3);   // XCD swizzle
  const int m0 = (bid / nbx) * 128, n0 = (bid % nbx) * 128;
  const int wr = wid >> 1, wc = wid & 1;
  const int lrow = lane & 15, lk = lane >> 4;

  const __hip_bfloat16* ag0 = A + (long)(m0 + wid * 16 + (lane >> 2)) * K + (lane & 3) * 8;
  const __hip_bfloat16* bg0 = Bt + (long)(n0 + wid * 16 + (lane >> 2)) * K + (lane & 3) * 8;
  const int off = wid * 1024 + lane * 16;

  f32x4 acc[4][4] = {};

  auto stage = [&](int k0, int bi) {
    gload_lds16(ag0 + k0,                     (char*)&a_lds[bi][0][0] + off);
    gload_lds16(ag0 + 64 * (long)K + k0,      (char*)&a_lds[bi][0][0] + off + 4096);
    gload_lds16(ag0 + k0 + 32,                (char*)&a_lds[bi][1][0] + off);
    gload_lds16(ag0 + 64 * (long)K + k0 + 32, (char*)&a_lds[bi][1][0] + off + 4096);
    gload_lds16(bg0 + k0,                     (char*)&b_lds[bi][0][0] + off);
    gload_lds16(bg0 + 64 * (long)K + k0,      (char*)&b_lds[bi][0][0] + off + 4096);
    gload_lds16(bg0 + k0 + 32,                (char*)&b_lds[bi][1][0] + off);
    gload_lds16(bg0 + 64 * (long)K + k0 + 32, (char*)&b_lds[bi][1][0] + off + 4096);
  };

  stage(0, 0);
  __syncthreads();
  int bi = 0;
  for (int k0 = 0; k0 < K; k0 += 64) {
    if (k0 + 64 < K) stage(k0 + 64, bi ^ 1);
#pragma unroll
    for (int hh = 0; hh < 2; hh++) {
      short8 af[4], bfr[4];
#pragma unroll
      for (int mi = 0; mi < 4; mi++)
        af[mi] = *(const short8*)(&a_lds[bi][hh][0] + (wr * 64 + mi * 16 + lrow) * 32 + lk * 8);
#pragma unroll
      for (int ni = 0; ni < 4; ni++)
        bfr[ni] = *(const short8*)(&b_lds[bi][hh][0] + (wc * 64 + ni * 16 + lrow) * 32 + lk * 8);
#pragma unroll
      for (int mi = 0; mi < 4; mi++)
#pragma unroll
        for (int ni = 0; ni < 4; ni++)
          acc[mi][ni] = mfma16(af[mi], bfr[ni], acc[mi][ni]);
    }
    __syncthreads();
    bi ^= 1;
  }
#pragma unroll
  for (int mi = 0; mi < 4; mi++)
#pragma unroll
    for (int ni = 0; ni < 4; ni++)
#pragma unroll
      for (int r = 0; r < 4; r++) {
        long row = m0 + wr * 64 + mi * 16 + lk * 4 + r;
        long col = n0 + wc * 64 + ni * 16 + lrow;
        storeC(C, row * N + col, acc[mi][ni][r]);
      }
}

// ---------------- fused RoPE + V-transpose ----------------
// Blocks [0,18432): rope (q pre-scaled by SCALE*log2e; k -> fragment-tiled k_t).
// Blocks [18432,19456): vtrans (v -> fragment-tiled v_t).
__global__ void rope_vtrans(const __hip_bfloat16* __restrict__ qkv,
                            const float* __restrict__ cost, const float* __restrict__ sint,
                            __hip_bfloat16* __restrict__ q_r, __hip_bfloat16* __restrict__ k_t,
                            __hip_bfloat16* __restrict__ v_t) {
  __shared__ __hip_bfloat16 t[32][33];
  const int bid = blockIdx.x;
  const int tid = threadIdx.x;
  if (bid < 18432) {
    long row = (long)bid * 4 + (tid >> 6);  // < 73728 = B*S*18
    int j = tid & 63;
    int hh = (int)(row % 18);
    long bs = row / 18;            // b*S + s
    int s = (int)(bs & (S_LEN - 1));
    int b = (int)(bs >> 11);
    const __hip_bfloat16* src = qkv + bs * NQKV;
    float c = cost[s * 64 + j], sn = sint[s * 64 + j];
    if (hh < NHEAD) {
      int col0 = hh * HDIM;
      float lo = __bfloat162float(src[col0 + j]);
      float hi = __bfloat162float(src[col0 + j + 64]);
      __hip_bfloat16* dst = q_r + ((long)(b * NHEAD + hh) * S_LEN + s) * HDIM;
      const float qs = SCALE * LOG2E;
      dst[j]      = __float2bfloat16((lo * c - hi * sn) * qs);
      dst[j + 64] = __float2bfloat16((hi * c + lo * sn) * qs);
    } else {
      int kvh = hh - NHEAD;
      int col0 = DMODEL + kvh * HDIM;
      float lo = __bfloat162float(src[col0 + j]);
      float hi = __bfloat162float(src[col0 + j + 64]);
      long tb = (long)(b * NKVH + kvh) * (S_LEN * HDIM) + (long)(s >> 5) * 4096 +
                (s & 15) * 8 + (j & 7);
      int cs4 = ((s >> 4) & 1) * 4;
      int lkq = ((j >> 3) & 3) * 16;
      int dch = j >> 5;   // 0 or 1 (j<64); high half d=j+64 -> dch+2
      k_t[tb + (long)((cs4 + dch) * 64 + lkq) * 8]     = __float2bfloat16(lo * c - hi * sn);
      k_t[tb + (long)((cs4 + dch + 2) * 64 + lkq) * 8] = __float2bfloat16(hi * c + lo * sn);
    }
  } else {
    int r = bid - 18432;            // 1024 blocks: st 0..63, dt 0..3, bk 0..3
    int st = r & 63, dt = (r >> 6) & 3, bk = r >> 8;
    int tx = tid & 31, ty = tid >> 5;
#pragma unroll
    for (int i = 0; i < 4; i++)
      t[ty + i * 8][tx] = qkv[((long)(bk >> 1) * S_LEN + st * 32 + ty + i * 8) * NQKV +
                              DMODEL + NKVH * HDIM + (bk & 1) * HDIM + dt * 32 + tx];
    __syncthreads();
    long base = (long)bk * (S_LEN * HDIM) + (long)st * 4096 + (tx >> 3) * 128 + (tx & 7);
#pragma unroll
    for (int i = 0; i < 4; i++) {
      int d = dt * 32 + ty + i * 8;
      v_t[base + (long)((d >> 4) * 64 + (d & 15)) * 8] = t[tx][ty + i * 8];
    }
  }
}

// ---------------- causal flash attention (R16 structure, measured-best) ----------------
__global__ __launch_bounds__(512, 2) void attn_kernel(
    const __hip_bfloat16* __restrict__ q_r, const __hip_bfloat16* __restrict__ k_t,
    const __hip_bfloat16* __restrict__ v_t, __hip_bfloat16* __restrict__ attn_a) {
  __shared__ __align__(16) __hip_bfloat16 k_st[2][4096];
  __shared__ __align__(16) __hip_bfloat16 v_st[2][4096];
  __shared__ __align__(16) __hip_bfloat16 p_lds[8][2 * 16 * 40];
  const int tid = threadIdx.x;
  const int wid = tid >> 6, lane = tid & 63;
  const int lrow = lane & 15, lk = lane >> 4;
  const int bidx = blockIdx.x;
  const int pr = bidx & 31;
  const int hg = (bidx >> 5) & 1;
  const int kv = (bidx >> 6) & 1;
  const int b = bidx >> 7;
  const int myc = (wid < 4) ? pr : (63 - pr);     // 32-row chunk index
  const int h = kv + 2 * (hg * 4 + (wid & 3));    // jnp.tile: head h uses kv h % HKV
  const int q0 = myc * 32;
  const int nkt_w = myc + 1;
  const int NV = 64 - pr;                         // staging iters (>= both nkt_w)

  const __hip_bfloat16* qb = q_r + (long)(b * NHEAD + h) * S_LEN * HDIM;
  const __hip_bfloat16* kbase = k_t + (long)(b * NKVH + kv) * (S_LEN * HDIM);
  const __hip_bfloat16* vbase = v_t + (long)(b * NKVH + kv) * (S_LEN * HDIM);

  char* kd0 = (char*)&k_st[0][0] + tid * 16;
  char* kd1 = (char*)&k_st[1][0] + tid * 16;
  char* vd0 = (char*)&v_st[0][0] + tid * 16;
  char* vd1 = (char*)&v_st[1][0] + tid * 16;

  // Q fragments (pre-scaled by SCALE*log2e); MFMA B-operand, q-col = lrow
  short8 qf[2][4];
#pragma unroll
  for (int m = 0; m < 2; m++)
#pragma unroll
    for (int dc = 0; dc < 4; dc++)
      qf[m][dc] = *(const short8*)(qb + (long)(q0 + m * 16 + lrow) * HDIM + dc * 32 + lk * 8);

  f32x4 oacc[2][8] = {};
  float mrow[2] = {5.77f, 5.77f};  // defer-max init (log2 domain)
  float lsum[2] = {0.f, 0.f};

  gload_lds16(kbase + tid * 8, kd0);
  gload_lds16(vbase + tid * 8, vd0);
  __syncthreads();

  for (int kt = 0; kt < NV; kt++) {
    const char* ks = (const char*)&k_st[kt & 1][0];
    const char* vs = (const char*)&v_st[kt & 1][0];
    if (kt + 1 < NV) {
      gload_lds16(kbase + (long)(kt + 1) * 4096 + tid * 8, (kt & 1) ? kd0 : kd1);
      gload_lds16(vbase + (long)(kt + 1) * 4096 + tid * 8, (kt & 1) ? vd0 : vd1);
    }
    if (kt < nkt_w) {
      const int kc0 = kt * 32;
      // K fragments: subtile (cs*4+dc), lane-linear -> conflict-free
      short8 kf[2][4];
#pragma unroll
      for (int cs = 0; cs < 2; cs++)
#pragma unroll
        for (int dc = 0; dc < 4; dc++)
          kf[cs][dc] = *(const short8*)(ks + ((cs * 4 + dc) * 64 + lane) * 16);
      // V fragments hoisted: ds_read latency hides under QK^T + softmax
      short8 vf[8];
#pragma unroll
      for (int d2 = 0; d2 < 8; d2++)
        vf[d2] = *(const short8*)(vs + (d2 * 64 + lane) * 16);
      // swapped QK^T: S^T; lane = q-col lrow, k-row = kc0 + cs*16 + lk*4 + r
      f32x4 sacc[2][2] = {};
#pragma unroll
      for (int dc = 0; dc < 4; dc++) {
        sacc[0][0] = mfma16(kf[0][dc], qf[0][dc], sacc[0][0]);
        sacc[0][1] = mfma16(kf[1][dc], qf[0][dc], sacc[0][1]);
        sacc[1][0] = mfma16(kf[0][dc], qf[1][dc], sacc[1][0]);
        sacc[1][1] = mfma16(kf[1][dc], qf[1][dc], sacc[1][1]);
      }
      const bool diag = (kt == nkt_w - 1);
#pragma unroll
      for (int m = 0; m < 2; m++) {
        float pv[8];
#pragma unroll
        for (int cs = 0; cs < 2; cs++)
#pragma unroll
          for (int r = 0; r < 4; r++) pv[cs * 4 + r] = sacc[m][cs][r];
        if (diag) {
          int qrow = q0 + m * 16 + lrow;
#pragma unroll
          for (int cs = 0; cs < 2; cs++)
#pragma unroll
            for (int r = 0; r < 4; r++)
              if (kc0 + cs * 16 + lk * 4 + r > qrow) pv[cs * 4 + r] = -3.0e38f;
        }
        float mx = fmaxf(fmaxf(fmaxf(pv[0], pv[1]), fmaxf(pv[2], pv[3])),
                         fmaxf(fmaxf(pv[4], pv[5]), fmaxf(pv[6], pv[7])));
        if (__builtin_expect(__any(mx > mrow[m] + 11.55f), 0)) {  // e^8 headroom, log2 units
          float mr = fmaxf(mx, __shfl_xor(mx, 16));
          mr = fmaxf(mr, __shfl_xor(mr, 32));
          float mnew = fmaxf(mrow[m], mr);
          float fr = fast_exp2(mrow[m] - mnew);
          lsum[m] *= fr;
          mrow[m] = mnew;
#pragma unroll
          for (int r2 = 0; r2 < 4; r2++) {
            float fro = __shfl(fr, lk * 4 + r2);
#pragma unroll
            for (int d2 = 0; d2 < 8; d2++) oacc[m][d2][r2] *= fro;
          }
        }
        float pe[8];
#pragma unroll
        for (int i = 0; i < 8; i++) pe[i] = fast_exp2(pv[i] - mrow[m]);
        lsum[m] += ((pe[0] + pe[1]) + (pe[2] + pe[3])) + ((pe[4] + pe[5]) + (pe[6] + pe[7]));
        unsigned short pk[8];
#pragma unroll
        for (int i = 0; i < 8; i++) pk[i] = bf16bits(pe[i]);
        *(ushort4*)(&p_lds[wid][(m * 16 + lrow) * 40 + lk * 4]) = *(ushort4*)&pk[0];
        *(ushort4*)(&p_lds[wid][(m * 16 + lrow) * 40 + 16 + lk * 4]) = *(ushort4*)&pk[4];
      }
      // PV: P as A-operand, V fragments already in registers
      short8 pf[2];
#pragma unroll
      for (int m = 0; m < 2; m++)
        pf[m] = *(const short8*)(&p_lds[wid][(m * 16 + lrow) * 40 + lk * 8]);
#pragma unroll
      for (int d2 = 0; d2 < 8; d2++) {
        oacc[0][d2] = mfma16(pf[0], vf[d2], oacc[0][d2]);
        oacc[1][d2] = mfma16(pf[1], vf[d2], oacc[1][d2]);
      }
    }
    __syncthreads();
  }

  // epilogue: reduce lsum across the 4 k-lane-groups, normalize, store
#pragma unroll
  for (int m = 0; m < 2; m++) {
    float ls = lsum[m];
    ls += __shfl_xor(ls, 16);
    ls += __shfl_xor(ls, 32);
    float inv = 1.0f / ls;  // valid for q-row = lrow
#pragma unroll
    for (int r = 0; r < 4; r++) {
      float invr = __shfl(inv, lk * 4 + r);  // oacc rows indexed by lk*4+r
      long row = (long)b * S_LEN + q0 + m * 16 + lk * 4 + r;
#pragma unroll
      for (int d2 = 0; d2 < 8; d2++)
        attn_a[row * DMODEL + h * HDIM + d2 * 16 + lrow] =
            __float2bfloat16(oacc[m][d2][r] * invr);
    }
  }
}

extern "C" void kernel_launch(void* const* d_in, const int* in_sizes, int n_in,
                              void* d_out, int out_size, void* d_ws, size_t ws_size,
                              hipStream_t stream) {
  const float* x  = (const float*)d_in[0];
  // d_in[1] = mask (tril causal) — computed analytically, unused
  const float* Wq = (const float*)d_in[2];
  const float* Wk = (const float*)d_in[3];
  const float* Wv = (const float*)d_in[4];
  const float* Wo = (const float*)d_in[5];
  float* out = (float*)d_out;

  char* ws = (char*)d_ws;
  __hip_bfloat16* xb     = (__hip_bfloat16*)(ws + 0);          // 16 MB; reused as attn_a
  __hip_bfloat16* attn_a = xb;
  __hip_bfloat16* wt1    = (__hip_bfloat16*)(ws + 16777216);   // 10 MB  [2560][2048]
  __hip_bfloat16* wto    = (__hip_bfloat16*)(ws + 27262976);   // 8 MB   [2048][2048]
  __hip_bfloat16* qkv    = (__hip_bfloat16*)(ws + 35651584);   // 20 MB  [4096][2560]
  __hip_bfloat16* q_r    = (__hip_bfloat16*)(ws + 56623104);   // 16 MB  [B][H][S][HD]
  __hip_bfloat16* k_t    = (__hip_bfloat16*)(ws + 73400320);   // 2 MB   fragment-tiled
  __hip_bfloat16* v_t    = (__hip_bfloat16*)(ws + 75497472);   // 2 MB   fragment-tiled
  float* cost            = (float*)(ws + 77594624);            // 512 KB [S][64]
  float* sint            = (float*)(ws + 78118912);            // 512 KB

  prep_kernel<<<17920, 256, 0, stream>>>(x, xb, Wq, Wk, Wv, wt1, Wo, wto, cost, sint);

  gemm_bt<__hip_bfloat16><<<dim3(20, 32), 256, 0, stream>>>(xb, wt1, qkv, NROW, NQKV, DMODEL);

  rope_vtrans<<<19456, 256, 0, stream>>>(qkv, cost, sint, q_r, k_t, v_t);

  attn_kernel<<<256, 512, 0, stream>>>(q_r, k_t, v_t, attn_a);

  gemm_bt<float><<<dim3(16, 32), 256, 0, stream>>>(attn_a, wto, out, NROW, DMODEL, DMODEL);
}

// Round 22
// 181.737 us; speedup vs baseline: 1.1015x; 1.1015x over previous
//
#include <hip/hip_runtime.h>
#include <hip/hip_bf16.h>

#define S_LEN 2048
#define DMODEL 2048
#define NHEAD 16
#define NKVH 2
#define HDIM 128
#define NROW 4096   // B*S
#define NQKV 2560   // 2048 + 256 + 256
#define SCALE 0.08838834764831845f
#define LOG2E 1.4426950408889634f

using short8 = __attribute__((ext_vector_type(8))) short;
using bf16x8 = __attribute__((ext_vector_type(8))) __bf16;
using f32x4  = __attribute__((ext_vector_type(4))) float;

__device__ __forceinline__ f32x4 mfma16(short8 a, short8 b, f32x4 c) {
  return __builtin_amdgcn_mfma_f32_16x16x32_bf16(
      __builtin_bit_cast(bf16x8, a), __builtin_bit_cast(bf16x8, b), c, 0, 0, 0);
}

__device__ __forceinline__ void gload_lds16(const void* g, void* l) {
  __builtin_amdgcn_global_load_lds(
      (const __attribute__((address_space(1))) unsigned int*)g,
      (__attribute__((address_space(3))) unsigned int*)l, 16, 0, 0);
}

__device__ __forceinline__ float fast_exp2(float x) {
  return __builtin_amdgcn_exp2f(x);   // raw v_exp_f32 (2^x), no libm wrapper
}

__device__ __forceinline__ void storeC(float* C, long idx, float v) { C[idx] = v; }
__device__ __forceinline__ void storeC(__hip_bfloat16* C, long idx, float v) {
  C[idx] = __float2bfloat16(v);
}

__device__ __forceinline__ unsigned short bf16bits(float f) {
  __hip_bfloat16 h = __float2bfloat16(f);
  return *(unsigned short*)&h;
}

// ---------------- fused prep: conv_x | convT3(Wq,Wk,Wv) | convT(Wo) | mk_table ----------------
__global__ void prep_kernel(const float* __restrict__ x, __hip_bfloat16* __restrict__ xb,
                            const float* __restrict__ Wq, const float* __restrict__ Wk,
                            const float* __restrict__ Wv, __hip_bfloat16* __restrict__ wt1,
                            const float* __restrict__ Wo, __hip_bfloat16* __restrict__ wto,
                            float* __restrict__ cost, float* __restrict__ sint) {
  __shared__ float t[32][33];
  const int bid = blockIdx.x;
  const int tid = threadIdx.x;
  if (bid < 8192) {
    long i = ((long)bid * 256 + tid) * 4;
    float4 v = *(const float4*)(x + i);
    __hip_bfloat16 o[4];
    o[0] = __float2bfloat16(v.x); o[1] = __float2bfloat16(v.y);
    o[2] = __float2bfloat16(v.z); o[3] = __float2bfloat16(v.w);
    *(ushort4*)(xb + i) = *(const ushort4*)o;
  } else if (bid < 17408) {
    int tx = tid & 31, ty = tid >> 5;
    const float* src; int Ns, n0, row_off, kt;
    __hip_bfloat16* dst;
    if (bid < 13312) {
      int r = bid - 8192;            // 5120 blocks: nt 0..79, kt 0..63
      int nt = r % 80; kt = r / 80;
      dst = wt1;
      if (nt < 64)      { src = Wq; Ns = 2048; n0 = nt * 32;        row_off = n0; }
      else if (nt < 72) { src = Wk; Ns = 256;  n0 = (nt - 64) * 32; row_off = 2048 + n0; }
      else              { src = Wv; Ns = 256;  n0 = (nt - 72) * 32; row_off = 2304 + n0; }
    } else {
      int r = bid - 13312;           // 4096 blocks
      int nt = r % 64; kt = r / 64;
      src = Wo; Ns = 2048; n0 = nt * 32; row_off = n0;
      dst = wto;
    }
#pragma unroll
    for (int i = 0; i < 4; i++)
      t[ty + i * 8][tx] = src[(long)(kt * 32 + ty + i * 8) * Ns + n0 + tx];
    __syncthreads();
#pragma unroll
    for (int i = 0; i < 4; i++)
      dst[(long)(row_off + ty + i * 8) * 2048 + kt * 32 + tx] =
          __float2bfloat16(t[tx][ty + i * 8]);
  } else {
    int i = (bid - 17408) * 256 + tid;  // < 131072
    int s = i >> 6, j = i & 63;
    float f = powf(10000.0f, -(float)j / 64.0f);
    float a = (float)s * f;
    cost[i] = cosf(a);
    sint[i] = sinf(a);
  }
}

// ---------------- m97-style GEMM, BK=64 via twin 32-K sub-tiles ----------------
template <typename OutT>
__global__ void gemm_bt(const __hip_bfloat16* __restrict__ A,
                        const __hip_bfloat16* __restrict__ Bt,
                        OutT* __restrict__ C, int M, int N, int K) {
  __shared__ __align__(16) __hip_bfloat16 a_lds[2][128 * 32];
  __shared__ __align__(16) __hip_bfloat16 b_lds[2][128 * 32];
  const int tid = threadIdx.x;
  const int wid = tid >> 6, lane = tid & 63;
  const int nbx = gridDim.x;
  int bid = blockIdx.y * nbx + blockIdx.x;
  const int nwg = nbx * gridDim.y;
  bid = (bid & 7) * (nwg >> 3) + (bid >> 3);   // XCD swizzle
  const int m0 = (bid / nbx) * 128, n0 = (bid % nbx) * 128;
  const int wr = wid >> 1, wc = wid & 1;
  const int lrow = lane & 15, lk = lane >> 4;

  const __hip_bfloat16* ag0 = A + (long)(m0 + wid * 16 + (lane >> 2)) * K + (lane & 3) * 8;
  const __hip_bfloat16* bg0 = Bt + (long)(n0 + wid * 16 + (lane >> 2)) * K + (lane & 3) * 8;
  char* al0 = (char*)&a_lds[0][0] + wid * 1024 + lane * 16;
  char* al1 = (char*)&a_lds[1][0] + wid * 1024 + lane * 16;
  char* bl0 = (char*)&b_lds[0][0] + wid * 1024 + lane * 16;
  char* bl1 = (char*)&b_lds[1][0] + wid * 1024 + lane * 16;

  f32x4 acc[4][4] = {};

  for (int k0 = 0; k0 < K; k0 += 64) {
    gload_lds16(ag0 + k0, al0);
    gload_lds16(ag0 + 64 * (long)K + k0, al0 + 4096);
    gload_lds16(ag0 + k0 + 32, al1);
    gload_lds16(ag0 + 64 * (long)K + k0 + 32, al1 + 4096);
    gload_lds16(bg0 + k0, bl0);
    gload_lds16(bg0 + 64 * (long)K + k0, bl0 + 4096);
    gload_lds16(bg0 + k0 + 32, bl1);
    gload_lds16(bg0 + 64 * (long)K + k0 + 32, bl1 + 4096);
    __syncthreads();
#pragma unroll
    for (int hh = 0; hh < 2; hh++) {
      short8 af[4], bfr[4];
#pragma unroll
      for (int mi = 0; mi < 4; mi++)
        af[mi] = *(const short8*)(&a_lds[hh][0] + (wr * 64 + mi * 16 + lrow) * 32 + lk * 8);
#pragma unroll
      for (int ni = 0; ni < 4; ni++)
        bfr[ni] = *(const short8*)(&b_lds[hh][0] + (wc * 64 + ni * 16 + lrow) * 32 + lk * 8);
#pragma unroll
      for (int mi = 0; mi < 4; mi++)
#pragma unroll
        for (int ni = 0; ni < 4; ni++)
          acc[mi][ni] = mfma16(af[mi], bfr[ni], acc[mi][ni]);
    }
    __syncthreads();
  }
#pragma unroll
  for (int mi = 0; mi < 4; mi++)
#pragma unroll
    for (int ni = 0; ni < 4; ni++)
#pragma unroll
      for (int r = 0; r < 4; r++) {
        long row = m0 + wr * 64 + mi * 16 + lk * 4 + r;
        long col = n0 + wc * 64 + ni * 16 + lrow;
        storeC(C, row * N + col, acc[mi][ni][r]);
      }
}

// ---------------- fused RoPE + V-transpose ----------------
__global__ void rope_vtrans(const __hip_bfloat16* __restrict__ qkv,
                            const float* __restrict__ cost, const float* __restrict__ sint,
                            __hip_bfloat16* __restrict__ q_r, __hip_bfloat16* __restrict__ k_t,
                            __hip_bfloat16* __restrict__ v_t) {
  __shared__ __hip_bfloat16 t[32][33];
  const int bid = blockIdx.x;
  const int tid = threadIdx.x;
  if (bid < 18432) {
    long row = (long)bid * 4 + (tid >> 6);  // < 73728 = B*S*18
    int j = tid & 63;
    int hh = (int)(row % 18);
    long bs = row / 18;            // b*S + s
    int s = (int)(bs & (S_LEN - 1));
    int b = (int)(bs >> 11);
    const __hip_bfloat16* src = qkv + bs * NQKV;
    float c = cost[s * 64 + j], sn = sint[s * 64 + j];
    if (hh < NHEAD) {
      int col0 = hh * HDIM;
      float lo = __bfloat162float(src[col0 + j]);
      float hi = __bfloat162float(src[col0 + j + 64]);
      __hip_bfloat16* dst = q_r + ((long)(b * NHEAD + hh) * S_LEN + s) * HDIM;
      const float qs = SCALE * LOG2E;
      dst[j]      = __float2bfloat16((lo * c - hi * sn) * qs);
      dst[j + 64] = __float2bfloat16((hi * c + lo * sn) * qs);
    } else {
      int kvh = hh - NHEAD;
      int col0 = DMODEL + kvh * HDIM;
      float lo = __bfloat162float(src[col0 + j]);
      float hi = __bfloat162float(src[col0 + j + 64]);
      long tb = (long)(b * NKVH + kvh) * (S_LEN * HDIM) + (long)(s >> 5) * 4096 +
                (s & 15) * 8 + (j & 7);
      int cs4 = ((s >> 4) & 1) * 4;
      int lkq = ((j >> 3) & 3) * 16;
      int dch = j >> 5;   // 0 or 1 (j<64); high half d=j+64 -> dch+2
      k_t[tb + (long)((cs4 + dch) * 64 + lkq) * 8]     = __float2bfloat16(lo * c - hi * sn);
      k_t[tb + (long)((cs4 + dch + 2) * 64 + lkq) * 8] = __float2bfloat16(hi * c + lo * sn);
    }
  } else {
    int r = bid - 18432;            // 1024 blocks: st 0..63, dt 0..3, bk 0..3
    int st = r & 63, dt = (r >> 6) & 3, bk = r >> 8;
    int tx = tid & 31, ty = tid >> 5;
#pragma unroll
    for (int i = 0; i < 4; i++)
      t[ty + i * 8][tx] = qkv[((long)(bk >> 1) * S_LEN + st * 32 + ty + i * 8) * NQKV +
                              DMODEL + NKVH * HDIM + (bk & 1) * HDIM + dt * 32 + tx];
    __syncthreads();
    long base = (long)bk * (S_LEN * HDIM) + (long)st * 4096 + (tx >> 3) * 128 + (tx & 7);
#pragma unroll
    for (int i = 0; i < 4; i++) {
      int d = dt * 32 + ty + i * 8;
      v_t[base + (long)((d >> 4) * 64 + (d & 15)) * 8] = t[tx][ty + i * 8];
    }
  }
}

// ---------------- causal flash attention (R16 structure, measured-best) ----------------
__global__ __launch_bounds__(512, 2) void attn_kernel(
    const __hip_bfloat16* __restrict__ q_r, const __hip_bfloat16* __restrict__ k_t,
    const __hip_bfloat16* __restrict__ v_t, __hip_bfloat16* __restrict__ attn_a) {
  __shared__ __align__(16) __hip_bfloat16 k_st[2][4096];
  __shared__ __align__(16) __hip_bfloat16 v_st[2][4096];
  __shared__ __align__(16) __hip_bfloat16 p_lds[8][2 * 16 * 40];
  const int tid = threadIdx.x;
  const int wid = tid >> 6, lane = tid & 63;
  const int lrow = lane & 15, lk = lane >> 4;
  const int bidx = blockIdx.x;
  const int pr = bidx & 31;
  const int hg = (bidx >> 5) & 1;
  const int kv = (bidx >> 6) & 1;
  const int b = bidx >> 7;
  const int myc = (wid < 4) ? pr : (63 - pr);     // 32-row chunk index
  const int h = kv + 2 * (hg * 4 + (wid & 3));    // jnp.tile: head h uses kv h % HKV
  const int q0 = myc * 32;
  const int nkt_w = myc + 1;
  const int NV = 64 - pr;                         // staging iters (>= both nkt_w)

  const __hip_bfloat16* qb = q_r + (long)(b * NHEAD + h) * S_LEN * HDIM;
  const __hip_bfloat16* kbase = k_t + (long)(b * NKVH + kv) * (S_LEN * HDIM);
  const __hip_bfloat16* vbase = v_t + (long)(b * NKVH + kv) * (S_LEN * HDIM);

  char* kd0 = (char*)&k_st[0][0] + tid * 16;
  char* kd1 = (char*)&k_st[1][0] + tid * 16;
  char* vd0 = (char*)&v_st[0][0] + tid * 16;
  char* vd1 = (char*)&v_st[1][0] + tid * 16;

  // Q fragments (pre-scaled by SCALE*log2e); MFMA B-operand, q-col = lrow
  short8 qf[2][4];
#pragma unroll
  for (int m = 0; m < 2; m++)
#pragma unroll
    for (int dc = 0; dc < 4; dc++)
      qf[m][dc] = *(const short8*)(qb + (long)(q0 + m * 16 + lrow) * HDIM + dc * 32 + lk * 8);

  f32x4 oacc[2][8] = {};
  float mrow[2] = {5.77f, 5.77f};  // defer-max init (log2 domain)
  float lsum[2] = {0.f, 0.f};

  gload_lds16(kbase + tid * 8, kd0);
  gload_lds16(vbase + tid * 8, vd0);
  __syncthreads();

  for (int kt = 0; kt < NV; kt++) {
    const char* ks = (const char*)&k_st[kt & 1][0];
    const char* vs = (const char*)&v_st[kt & 1][0];
    if (kt + 1 < NV) {
      gload_lds16(kbase + (long)(kt + 1) * 4096 + tid * 8, (kt & 1) ? kd0 : kd1);
      gload_lds16(vbase + (long)(kt + 1) * 4096 + tid * 8, (kt & 1) ? vd0 : vd1);
    }
    if (kt < nkt_w) {
      const int kc0 = kt * 32;
      // K fragments: subtile (cs*4+dc), lane-linear -> conflict-free
      short8 kf[2][4];
#pragma unroll
      for (int cs = 0; cs < 2; cs++)
#pragma unroll
        for (int dc = 0; dc < 4; dc++)
          kf[cs][dc] = *(const short8*)(ks + ((cs * 4 + dc) * 64 + lane) * 16);
      // V fragments hoisted: ds_read latency hides under QK^T + softmax
      short8 vf[8];
#pragma unroll
      for (int d2 = 0; d2 < 8; d2++)
        vf[d2] = *(const short8*)(vs + (d2 * 64 + lane) * 16);
      // swapped QK^T: S^T; lane = q-col lrow, k-row = kc0 + cs*16 + lk*4 + r
      f32x4 sacc[2][2] = {};
#pragma unroll
      for (int dc = 0; dc < 4; dc++) {
        sacc[0][0] = mfma16(kf[0][dc], qf[0][dc], sacc[0][0]);
        sacc[0][1] = mfma16(kf[1][dc], qf[0][dc], sacc[0][1]);
        sacc[1][0] = mfma16(kf[0][dc], qf[1][dc], sacc[1][0]);
        sacc[1][1] = mfma16(kf[1][dc], qf[1][dc], sacc[1][1]);
      }
      const bool diag = (kt == nkt_w - 1);
#pragma unroll
      for (int m = 0; m < 2; m++) {
        float pv[8];
#pragma unroll
        for (int cs = 0; cs < 2; cs++)
#pragma unroll
          for (int r = 0; r < 4; r++) pv[cs * 4 + r] = sacc[m][cs][r];
        if (diag) {
          int qrow = q0 + m * 16 + lrow;
#pragma unroll
          for (int cs = 0; cs < 2; cs++)
#pragma unroll
            for (int r = 0; r < 4; r++)
              if (kc0 + cs * 16 + lk * 4 + r > qrow) pv[cs * 4 + r] = -3.0e38f;
        }
        float mx = fmaxf(fmaxf(fmaxf(pv[0], pv[1]), fmaxf(pv[2], pv[3])),
                         fmaxf(fmaxf(pv[4], pv[5]), fmaxf(pv[6], pv[7])));
        if (__builtin_expect(__any(mx > mrow[m] + 11.55f), 0)) {  // e^8 headroom, log2 units
          float mr = fmaxf(mx, __shfl_xor(mx, 16));
          mr = fmaxf(mr, __shfl_xor(mr, 32));
          float mnew = fmaxf(mrow[m], mr);
          float fr = fast_exp2(mrow[m] - mnew);
          lsum[m] *= fr;
          mrow[m] = mnew;
#pragma unroll
          for (int r2 = 0; r2 < 4; r2++) {
            float fro = __shfl(fr, lk * 4 + r2);
#pragma unroll
            for (int d2 = 0; d2 < 8; d2++) oacc[m][d2][r2] *= fro;
          }
        }
        float pe[8];
#pragma unroll
        for (int i = 0; i < 8; i++) pe[i] = fast_exp2(pv[i] - mrow[m]);
        lsum[m] += ((pe[0] + pe[1]) + (pe[2] + pe[3])) + ((pe[4] + pe[5]) + (pe[6] + pe[7]));
        unsigned short pk[8];
#pragma unroll
        for (int i = 0; i < 8; i++) pk[i] = bf16bits(pe[i]);
        *(ushort4*)(&p_lds[wid][(m * 16 + lrow) * 40 + lk * 4]) = *(ushort4*)&pk[0];
        *(ushort4*)(&p_lds[wid][(m * 16 + lrow) * 40 + 16 + lk * 4]) = *(ushort4*)&pk[4];
      }
      // PV: P as A-operand, V fragments already in registers
      short8 pf[2];
#pragma unroll
      for (int m = 0; m < 2; m++)
        pf[m] = *(const short8*)(&p_lds[wid][(m * 16 + lrow) * 40 + lk * 8]);
#pragma unroll
      for (int d2 = 0; d2 < 8; d2++) {
        oacc[0][d2] = mfma16(pf[0], vf[d2], oacc[0][d2]);
        oacc[1][d2] = mfma16(pf[1], vf[d2], oacc[1][d2]);
      }
    }
    __syncthreads();
  }

  // epilogue: reduce lsum across the 4 k-lane-groups, normalize, store
#pragma unroll
  for (int m = 0; m < 2; m++) {
    float ls = lsum[m];
    ls += __shfl_xor(ls, 16);
    ls += __shfl_xor(ls, 32);
    float inv = 1.0f / ls;  // valid for q-row = lrow
#pragma unroll
    for (int r = 0; r < 4; r++) {
      float invr = __shfl(inv, lk * 4 + r);  // oacc rows indexed by lk*4+r
      long row = (long)b * S_LEN + q0 + m * 16 + lk * 4 + r;
#pragma unroll
      for (int d2 = 0; d2 < 8; d2++)
        attn_a[row * DMODEL + h * HDIM + d2 * 16 + lrow] =
            __float2bfloat16(oacc[m][d2][r] * invr);
    }
  }
}

extern "C" void kernel_launch(void* const* d_in, const int* in_sizes, int n_in,
                              void* d_out, int out_size, void* d_ws, size_t ws_size,
                              hipStream_t stream) {
  const float* x  = (const float*)d_in[0];
  // d_in[1] = mask (tril causal) — computed analytically, unused
  const float* Wq = (const float*)d_in[2];
  const float* Wk = (const float*)d_in[3];
  const float* Wv = (const float*)d_in[4];
  const float* Wo = (const float*)d_in[5];
  float* out = (float*)d_out;

  char* ws = (char*)d_ws;
  __hip_bfloat16* xb     = (__hip_bfloat16*)(ws + 0);          // 16 MB; reused as attn_a
  __hip_bfloat16* attn_a = xb;
  __hip_bfloat16* wt1    = (__hip_bfloat16*)(ws + 16777216);   // 10 MB  [2560][2048]
  __hip_bfloat16* wto    = (__hip_bfloat16*)(ws + 27262976);   // 8 MB   [2048][2048]
  __hip_bfloat16* qkv    = (__hip_bfloat16*)(ws + 35651584);   // 20 MB  [4096][2560]
  __hip_bfloat16* q_r    = (__hip_bfloat16*)(ws + 56623104);   // 16 MB  [B][H][S][HD]
  __hip_bfloat16* k_t    = (__hip_bfloat16*)(ws + 73400320);   // 2 MB   fragment-tiled
  __hip_bfloat16* v_t    = (__hip_bfloat16*)(ws + 75497472);   // 2 MB   fragment-tiled
  float* cost            = (float*)(ws + 77594624);            // 512 KB [S][64]
  float* sint            = (float*)(ws + 78118912);            // 512 KB

  prep_kernel<<<17920, 256, 0, stream>>>(x, xb, Wq, Wk, Wv, wt1, Wo, wto, cost, sint);

  gemm_bt<__hip_bfloat16><<<dim3(20, 32), 256, 0, stream>>>(xb, wt1, qkv, NROW, NQKV, DMODEL);

  rope_vtrans<<<19456, 256, 0, stream>>>(qkv, cost, sint, q_r, k_t, v_t);

  attn_kernel<<<256, 512, 0, stream>>>(q_r, k_t, v_t, attn_a);

  gemm_bt<float><<<dim3(16, 32), 256, 0, stream>>>(attn_a, wto, out, NROW, DMODEL, DMODEL);
}